// Round 4
// baseline (15.629 us; speedup 1.0000x reference)
//
#include <hip/hip_runtime.h>

#define RWIN 5
#define TMAX 8192

// One block per row, 640 threads = 10 waves = 2 waves per adaptive-pool window.
// Window win = [floor(win*L/5), ceil((win+1)*L/5)). Loads are 4-aligned masked
// float4 (always within the row since e <= 8192), so there are no scalar
// head/tail loops. Wave butterfly -> LDS -> pairwise combine -> 10-elem rank sort.
__global__ __launch_bounds__(640) void minmax_sort_kernel(
    const float* __restrict__ in, const int* __restrict__ lengths,
    float* __restrict__ out)
{
    __shared__ float smx[2 * RWIN];
    __shared__ float smn[2 * RWIN];
    __shared__ float vals[2 * RWIN];

    const int b    = blockIdx.x;
    const int tid  = threadIdx.x;     // 0..639
    const int win  = tid >> 7;        // window 0..4 (128 threads each)
    const int t2   = tid & 127;       // lane within the 2-wave window team
    const int wid  = tid >> 6;        // wave id 0..9
    const int lane = tid & 63;

    const int L = __builtin_amdgcn_readfirstlane(lengths[b]);
    const float* rowp = in + (size_t)b * TMAX;

    const int s  = (win * L) / RWIN;                      // start (incl)
    const int e  = ((win + 1) * L + (RWIN - 1)) / RWIN;   // end (excl), >= s+1
    const int sa = s & ~3;                                // aligned start

    const float NINF = -__builtin_inff();
    const float PINF =  __builtin_inff();
    float mx = NINF;
    float mn = PINF;

    // <= 4 iterations (window span <= 1642 elems / 512 per iter).
    #pragma unroll 4
    for (int t = sa + t2 * 4; t < e; t += 128 * 4) {
        const float4 v = *reinterpret_cast<const float4*>(rowp + t);
        const float xs[4] = {v.x, v.y, v.z, v.w};
        #pragma unroll
        for (int j = 0; j < 4; ++j) {
            const int  idx = t + j;
            const bool ok  = (idx >= s) & (idx < e);
            mx = fmaxf(mx, ok ? xs[j] : NINF);
            mn = fminf(mn, ok ? xs[j] : PINF);
        }
    }

    // Wave-level butterfly (64 lanes).
    #pragma unroll
    for (int off = 1; off < 64; off <<= 1) {
        mx = fmaxf(mx, __shfl_xor(mx, off));
        mn = fminf(mn, __shfl_xor(mn, off));
    }
    if (lane == 0) { smx[wid] = mx; smn[wid] = mn; }
    __syncthreads();

    // Combine the 2 waves of each window; vals[0..4]=maxes, vals[5..9]=mins.
    if (tid < RWIN) {
        vals[tid] = fmaxf(smx[2 * tid], smx[2 * tid + 1]);
    } else if (tid < 2 * RWIN) {
        const int k = tid - RWIN;
        vals[tid] = fminf(smn[2 * k], smn[2 * k + 1]);
    }
    __syncthreads();

    // Rank sort of the 10 values (stable via index tie-break); ascending.
    if (tid < 2 * RWIN) {
        const float v = vals[tid];
        int pos = 0;
        #pragma unroll
        for (int j = 0; j < 2 * RWIN; ++j) {
            const float vj = vals[j];
            pos += (int)((vj < v) | ((vj == v) & (j < tid)));
        }
        out[b * (2 * RWIN) + pos] = v;
    }
}

extern "C" void kernel_launch(void* const* d_in, const int* in_sizes, int n_in,
                              void* d_out, int out_size, void* d_ws, size_t ws_size,
                              hipStream_t stream) {
    const float* in      = (const float*)d_in[0];
    const int*   lengths = (const int*)d_in[1];
    float*       out     = (float*)d_out;
    const int B = in_sizes[1];   // 2048 rows
    minmax_sort_kernel<<<B, 640, 0, stream>>>(in, lengths, out);
}